// Round 10
// baseline (3162.366 us; speedup 1.0000x reference)
//
#include <hip/hip_runtime.h>
#include <math.h>

// ---------------- problem constants (fixed by setup_inputs) ----------------
#define N_    256
#define T_    36
#define M_    50
#define P_    80
#define K_    161          // 1 + 2P
#define NP    3            // rotation pairs per lane (32 lanes * 3 = 96 slots:
                           //  80 real cos/sin pairs + k0 column + 15 pads)
#define KCV   6            // values per lane (2 per pair)
#define NBR   1600         // 1600 blocks * 4 waves * 2 cols = 12800 columns
#define NTR   256
#define LAM_  0.1f
#define MAXIT 100

#define KM_     (K_*M_)        // 8050
#define TM_     (T_*M_)        // 1800
#define OUT_DIC 2060800        // N*K*M
#define OUT_REC 2066596        // + T*K

// ---- workspace float offsets ----
#define WS_LINV 0
#define WS_AB   64             // 96 slots * 2 = 192 floats (a=r cos, b=r sin)
#define WS_ACC  8192           // 2 passes * 100 iters * 4 slots
#define WS_WN   9000
#define WS_NIT1 9002           // int: pass-1 replay count (101 = none)
#define WS_NIT2 9003

// slot s = sub*3+p:  s<80: cos k=1+s / sin k=81+s;  s==80: k=0 const;  s>80: pad
__device__ __forceinline__ int kcos_of(int s) { return (s < 80) ? 1 + s : (s == 80 ? 0 : -1); }
__device__ __forceinline__ int ksin_of(int s) { return (s < 80) ? 81 + s : -1; }

// ---------------------------------------------------------------------------
// kernel 1: dictionary output + Linv + rotation-constant table
// ---------------------------------------------------------------------------
__global__ __launch_bounds__(256) void k_dict(const float* __restrict__ rr,
                                              const float* __restrict__ th,
                                              float* __restrict__ out,
                                              float* __restrict__ ws) {
    __shared__ float Dl[T_*K_];
    const int tid = threadIdx.x;
    for (int e = tid; e < T_*K_; e += 256) {
        int t = e / K_, k = e - (e / K_) * K_;
        float v;
        if (k == 0) v = 1.f;
        else if (k <= P_)      { float r = rr[k-1];     float a = th[k-1]*(float)t;
                                 v = powf(r, (float)t) * cosf(a); }
        else                   { float r = rr[k-1-P_];  float a = th[k-1-P_]*(float)t;
                                 v = powf(r, (float)t) * sinf(a); }
        Dl[e] = v;
        out[OUT_DIC + t*K_ + k] = v;
    }
    // rotation constants: a = r cos(theta), b = r sin(theta) per slot
    if (tid < 96) {
        int s = tid;
        float a = 0.f, bb = 0.f;
        if (s < 80)      { float r = rr[s]; float t = th[s]; a = r*cosf(t); bb = r*sinf(t); }
        else if (s == 80){ a = 1.f; }
        ws[WS_AB + 2*s]     = a;
        ws[WS_AB + 2*s + 1] = bb;
    }
    __syncthreads();
    float loc = 0.f;
    for (int e = tid; e < T_*T_; e += 256) {
        int t1 = e / T_, t2 = e - (e / T_) * T_;
        float s = 0.f;
        for (int k = 0; k < K_; ++k) s = fmaf(Dl[t1*K_+k], Dl[t2*K_+k], s);
        loc = fmaf(s, s, loc);
    }
    #pragma unroll
    for (int mm = 1; mm < 64; mm <<= 1) loc += __shfl_xor(loc, mm);
    __shared__ float rb[4];
    if ((tid & 63) == 0) rb[tid >> 6] = loc;
    __syncthreads();
    if (tid == 0) {
        float tot = rb[0] + rb[1] + rb[2] + rb[3];
        ws[WS_LINV] = 1.0f / sqrtf(tot);   // 1/frob(DtD) via frob(D D^T)
    }
}

// ---- 32-lane sum: 4 DPP levels (16-lane) + one xor-16 shuffle --------------
template<int CTRL>
__device__ __forceinline__ float dpp_mov(float v) {
    int p = __builtin_amdgcn_update_dpp(0, __float_as_int(v), CTRL, 0xF, 0xF, true);
    return __int_as_float(p);
}
__device__ __forceinline__ float reduce32(float z) {
    z += dpp_mov<0xB1>(z);     // quad_perm xor1
    z += dpp_mov<0x4E>(z);     // quad_perm xor2
    z += dpp_mov<0x141>(z);    // row_half_mirror
    z += dpp_mov<0x140>(z);    // row_mirror -> 16-lane sums
    z += __shfl_xor(z, 16);    // cross the 16-boundary within each 32-group
    return z;
}

// per-thread geometry
struct Geo { int n0, m0, sub, lane, gw; };
__device__ __forceinline__ Geo make_geo() {
    Geo g;
    const int tid = threadIdx.x;
    g.lane = tid & 63;
    g.sub  = g.lane & 31;
    g.gw   = (int)blockIdx.x * (NTR/64) + (tid >> 6);
    const int col = g.gw*2 + (g.lane >> 5);        // [0, 12800)
    g.n0 = col / M_;  g.m0 = col - g.n0*M_;
    return g;
}

// init W to the t=0 dictionary row: real+k0 slots (1,0), pads (0,0)
__device__ __forceinline__ void winit(int sub, float (&W1)[NP], float (&W2)[NP]) {
    #pragma unroll
    for (int p = 0; p < NP; ++p) {
        int s = sub*NP + p;
        W1[p] = (s <= 80) ? 1.f : 0.f;
        W2[p] = 0.f;
    }
}
__device__ __forceinline__ void wrot(const float (&ap)[NP], const float (&bp)[NP],
                                     float (&W1)[NP], float (&W2)[NP]) {
    #pragma unroll
    for (int p = 0; p < NP; ++p) {
        float w1 = W1[p], w2 = W2[p];
        W1[p] = fmaf(ap[p], w1, -bp[p]*w2);
        W2[p] = fmaf(bp[p], w1,  ap[p]*w2);
    }
}

// b = Linv * D^T Ycol via rotation
__device__ __forceinline__ void compute_b(const float (&ap)[NP], const float (&bp)[NP],
                                          int sub, float Linv,
                                          const float* Y0, float (&b)[KCV]) {
    #pragma unroll
    for (int j = 0; j < KCV; ++j) b[j] = 0.f;
    float W1[NP], W2[NP];
    winit(sub, W1, W2);
    #pragma unroll 4
    for (int t = 0; t < T_; ++t) {
        float yv = Y0[t*M_];
        #pragma unroll
        for (int p = 0; p < NP; ++p) {
            b[2*p]   = fmaf(W1[p], yv, b[2*p]);
            b[2*p+1] = fmaf(W2[p], yv, b[2*p+1]);
        }
        wrot(ap, bp, W1, W2);
    }
    #pragma unroll
    for (int j = 0; j < KCV; ++j) b[j] *= Linv;
}

// ---------------------------------------------------------------------------
// k_run<PASS>: one pass, MAXIT iters, conv norms recorded, code written.
// No LDS; D regenerated by rotation; state ~55 VGPR -> RA-squeeze-proof.
// ---------------------------------------------------------------------------
template<int PASS>
__global__ __launch_bounds__(NTR, 1)
void k_run(const float* __restrict__ X,
           float* __restrict__ out,
           float* __restrict__ ws) {
    const float Linv = ws[WS_LINV];
    Geo g = make_geo();
    const float* Y0 = X + g.n0*TM_ + g.m0;

    float ap[NP], bp[NP];
    #pragma unroll
    for (int p = 0; p < NP; ++p) {
        int s = g.sub*NP + p;
        ap[p] = ws[WS_AB + 2*s];
        bp[p] = ws[WS_AB + 2*s + 1];
    }

    float x[KCV], y[KCV], cm[KCV], cp[KCV];
    const float wlc = LAM_ * Linv;

    compute_b(ap, bp, g.sub, Linv, Y0, cm);        // cm = b

    if (PASS == 1) {
        float scale = ((float)K_) * (LAM_ * Linv) / sqrtf(ws[WS_WN]);
        #pragma unroll
        for (int p = 0; p < NP; ++p) {
            int s = g.sub*NP + p;
            int kc = kcos_of(s), ks = ksin_of(s);
            float x1c = (kc >= 0) ? out[g.n0*KM_ + kc*M_ + g.m0] : 0.f;
            float x1s = (ks >= 0) ? out[g.n0*KM_ + ks*M_ + g.m0] : 0.f;
            float wlcv = scale / (fabsf(x1c) + 0.01f);
            float wlsv = scale / (fabsf(x1s) + 0.01f);
            float bc = cm[2*p], bs = cm[2*p+1];
            cm[2*p]   = bc - wlcv;  cp[2*p]   = bc + wlcv;
            cm[2*p+1] = bs - wlsv;  cp[2*p+1] = bs + wlsv;
        }
    }

    float tcur = 1.f;

    auto iterate = [&](float tt) -> float {
        float u[KCV];
        #pragma unroll
        for (int j = 0; j < KCV; ++j) u[j] = 0.f;
        float W1[NP], W2[NP];
        winit(g.sub, W1, W2);
        #pragma unroll 4
        for (int t = 0; t < T_; ++t) {
            float z = 0.f, z2 = 0.f;
            #pragma unroll
            for (int p = 0; p < NP; ++p) {
                z  = fmaf(W1[p], y[2*p],   z);
                z2 = fmaf(W2[p], y[2*p+1], z2);
            }
            z = reduce32(z + z2);                  // all 32 lanes hold z_t
            #pragma unroll
            for (int p = 0; p < NP; ++p) {
                u[2*p]   = fmaf(W1[p], z, u[2*p]);
                u[2*p+1] = fmaf(W2[p], z, u[2*p+1]);
            }
            wrot(ap, bp, W1, W2);
        }
        float ss = 0.f;
        #pragma unroll
        for (int j = 0; j < KCV; ++j) {
            float v = fmaf(-Linv, u[j], y[j]);     // Ay
            float xn;
            if (PASS == 0) {
                float s = v + cm[j];                // Ay + b
                xn = fmaxf(0.f, s - wlc) + fminf(0.f, s + wlc);
            } else {
                xn = fmaxf(0.f, v + cm[j]) + fminf(0.f, v + cp[j]);
            }
            float d = xn - x[j];
            ss   = fmaf(d, d, ss);
            y[j] = fmaf(tt, d, xn);
            x[j] = xn;
        }
        return ss;
    };

    #pragma unroll
    for (int j = 0; j < KCV; ++j) { x[j] = 0.f; y[j] = 0.f; }
    float* acc = ws + WS_ACC + PASS*4*MAXIT;
    for (int i = 0; i < MAXIT; ++i) {
        float tnext = 0.5f * (1.f + sqrtf(fmaf(4.f*tcur, tcur, 1.f)));
        float tt = (tcur - 1.f) / tnext;
        tcur = tnext;
        float ss = iterate(tt);
        ss = reduce32(ss);
        ss += __shfl_xor(ss, 32);
        if (g.lane == 0) atomicAdd(acc + i*4 + (g.gw & 3), ss);
    }

    // ---- write code ----
    #pragma unroll
    for (int p = 0; p < NP; ++p) {
        int s = g.sub*NP + p;
        int kc = kcos_of(s), ks = ksin_of(s);
        if (kc >= 0) out[g.n0*KM_ + kc*M_ + g.m0] = x[2*p];
        if (ks >= 0) out[g.n0*KM_ + ks*M_ + g.m0] = x[2*p+1];
    }
}

// generic FISTA run with per-element cm/cp (replay paths only)
__device__ __forceinline__ void run_fista(const float (&ap)[NP], const float (&bp)[NP],
                                          int sub, float Linv,
                                          const float (&cmv)[KCV], const float (&cpv)[KCV],
                                          float (&x)[KCV], int nit) {
    float y[KCV];
    #pragma unroll
    for (int j = 0; j < KCV; ++j) { x[j] = 0.f; y[j] = 0.f; }
    float tcur = 1.f;
    for (int i = 0; i < nit; ++i) {
        float tnext = 0.5f * (1.f + sqrtf(fmaf(4.f*tcur, tcur, 1.f)));
        float tt = (tcur - 1.f) / tnext;
        tcur = tnext;
        float u[KCV];
        #pragma unroll
        for (int j = 0; j < KCV; ++j) u[j] = 0.f;
        float W1[NP], W2[NP];
        winit(sub, W1, W2);
        #pragma unroll 4
        for (int t = 0; t < T_; ++t) {
            float z = 0.f, z2 = 0.f;
            #pragma unroll
            for (int p = 0; p < NP; ++p) {
                z  = fmaf(W1[p], y[2*p],   z);
                z2 = fmaf(W2[p], y[2*p+1], z2);
            }
            z = reduce32(z + z2);
            #pragma unroll
            for (int p = 0; p < NP; ++p) {
                u[2*p]   = fmaf(W1[p], z, u[2*p]);
                u[2*p+1] = fmaf(W2[p], z, u[2*p+1]);
            }
            wrot(ap, bp, W1, W2);
        }
        #pragma unroll
        for (int j = 0; j < KCV; ++j) {
            float v = fmaf(-Linv, u[j], y[j]);
            float xn = fmaxf(0.f, v + cmv[j]) + fminf(0.f, v + cpv[j]);
            float d = xn - x[j];
            y[j] = fmaf(tt, d, xn);
            x[j] = xn;
        }
    }
}

__device__ __forceinline__ void load_ab(const float* ws, int sub,
                                        float (&ap)[NP], float (&bp)[NP]) {
    #pragma unroll
    for (int p = 0; p < NP; ++p) {
        int s = sub*NP + p;
        ap[p] = ws[WS_AB + 2*s];
        bp[p] = ws[WS_AB + 2*s + 1];
    }
}
__device__ __forceinline__ void write_code_g(const Geo& g, const float (&x)[KCV],
                                             float* out) {
    #pragma unroll
    for (int p = 0; p < NP; ++p) {
        int s = g.sub*NP + p;
        int kc = kcos_of(s), ks = ksin_of(s);
        if (kc >= 0) out[g.n0*KM_ + kc*M_ + g.m0] = x[2*p];
        if (ks >= 0) out[g.n0*KM_ + ks*M_ + g.m0] = x[2*p+1];
    }
}
__device__ __forceinline__ void load_code_g(const Geo& g, float (&x)[KCV],
                                            const float* out) {
    #pragma unroll
    for (int p = 0; p < NP; ++p) {
        int s = g.sub*NP + p;
        int kc = kcos_of(s), ks = ksin_of(s);
        x[2*p]   = (kc >= 0) ? out[g.n0*KM_ + kc*M_ + g.m0] : 0.f;
        x[2*p+1] = (ks >= 0) ? out[g.n0*KM_ + ks*M_ + g.m0] : 0.f;
    }
}

// ---------------------------------------------------------------------------
__global__ void k_scan(float* __restrict__ ws, int pass) {
    const float THR2 = (1e-5f * (float)K_) * (1e-5f * (float)K_);
    int lane = threadIdx.x;
    const float* acc = ws + WS_ACC + pass*4*MAXIT;
    int best = MAXIT + 1;
    for (int i = lane; i < MAXIT; i += 64) {
        float a = (acc[i*4] + acc[i*4+1]) + (acc[i*4+2] + acc[i*4+3]);
        if (a < THR2) best = min(best, i + 1);
    }
    #pragma unroll
    for (int mm = 1; mm < 64; mm <<= 1) best = min(best, __shfl_xor(best, mm));
    if (lane == 0) ((int*)ws)[pass == 0 ? WS_NIT1 : WS_NIT2] = best;
}

// ---------------------------------------------------------------------------
__global__ __launch_bounds__(NTR, 1) void k_fin1(const float* __restrict__ X,
                                                 float* __restrict__ out,
                                                 float* __restrict__ ws) {
    const float Linv = ws[WS_LINV];
    Geo g = make_geo();
    const int nit1 = ((const int*)ws)[WS_NIT1];
    float ap[NP], bp[NP];
    load_ab(ws, g.sub, ap, bp);
    float x[KCV];

    if (nit1 <= MAXIT) {
        float b[KCV], cmv[KCV], cpv[KCV];
        compute_b(ap, bp, g.sub, Linv, X + g.n0*TM_ + g.m0, b);
        const float wlc = LAM_ * Linv;
        #pragma unroll
        for (int j = 0; j < KCV; ++j) { cmv[j] = b[j] - wlc; cpv[j] = b[j] + wlc; }
        run_fista(ap, bp, g.sub, Linv, cmv, cpv, x, nit1);
        write_code_g(g, x, out);
    } else {
        load_code_g(g, x, out);
    }

    // ||wn||^2 over valid k only
    float loc = 0.f;
    #pragma unroll
    for (int p = 0; p < NP; ++p) {
        int s = g.sub*NP + p;
        if (kcos_of(s) >= 0) { float wn = 1.f/(fabsf(x[2*p])+0.01f);   loc = fmaf(wn,wn,loc); }
        if (ksin_of(s) >= 0) { float wn = 1.f/(fabsf(x[2*p+1])+0.01f); loc = fmaf(wn,wn,loc); }
    }
    #pragma unroll
    for (int mm = 1; mm < 64; mm <<= 1) loc += __shfl_xor(loc, mm);
    if (g.lane == 0) atomicAdd(ws + WS_WN, loc);
}

// ---------------------------------------------------------------------------
__global__ __launch_bounds__(NTR, 1) void k_fin2(const float* __restrict__ X,
                                                 float* __restrict__ out,
                                                 float* __restrict__ ws) {
    const float Linv = ws[WS_LINV];
    Geo g = make_geo();
    const int nit1 = ((const int*)ws)[WS_NIT1];
    const int nit2 = ((const int*)ws)[WS_NIT2];
    float ap[NP], bp[NP];
    load_ab(ws, g.sub, ap, bp);
    float x[KCV];

    if (nit2 <= MAXIT) {
        float b[KCV], cmv[KCV], cpv[KCV];
        compute_b(ap, bp, g.sub, Linv, X + g.n0*TM_ + g.m0, b);
        const float wlc = LAM_ * Linv;
        #pragma unroll
        for (int j = 0; j < KCV; ++j) { cmv[j] = b[j] - wlc; cpv[j] = b[j] + wlc; }
        int nrep1 = nit1 <= MAXIT ? nit1 : MAXIT;
        run_fista(ap, bp, g.sub, Linv, cmv, cpv, x, nrep1);
        float scale = ((float)K_) * (LAM_ * Linv) / sqrtf(ws[WS_WN]);
        #pragma unroll
        for (int j = 0; j < KCV; ++j) {
            float wl = scale / (fabsf(x[j]) + 0.01f);
            cmv[j] = b[j] - wl;
            cpv[j] = b[j] + wl;
        }
        run_fista(ap, bp, g.sub, Linv, cmv, cpv, x, nit2);
        write_code_g(g, x, out);
    } else {
        load_code_g(g, x, out);
    }

    // ---- reconst = D @ code via rotation ----
    float W1[NP], W2[NP];
    winit(g.sub, W1, W2);
    for (int t = 0; t < T_; ++t) {
        float z = 0.f, z2 = 0.f;
        #pragma unroll
        for (int p = 0; p < NP; ++p) {
            z  = fmaf(W1[p], x[2*p],   z);
            z2 = fmaf(W2[p], x[2*p+1], z2);
        }
        z = reduce32(z + z2);
        if (g.sub == (t & 31)) out[OUT_REC + g.n0*TM_ + t*M_ + g.m0] = z;
        wrot(ap, bp, W1, W2);
    }
}

// ---------------------------------------------------------------------------
extern "C" void kernel_launch(void* const* d_in, const int* in_sizes, int n_in,
                              void* d_out, int out_size, void* d_ws, size_t ws_size,
                              hipStream_t stream) {
    const float* X  = (const float*)d_in[0];
    const float* rr = (const float*)d_in[1];
    const float* th = (const float*)d_in[2];
    float* out = (float*)d_out;
    float* ws  = (float*)d_ws;

    // zero conv accumulators + wn accumulator + niter slots (every call)
    hipMemsetAsync((char*)d_ws + WS_ACC*sizeof(float), 0, 4096, stream);
    k_dict  <<<dim3(1),   dim3(256), 0, stream>>>(rr, th, out, ws);
    k_run<0><<<dim3(NBR), dim3(NTR), 0, stream>>>(X, out, ws);
    k_scan  <<<dim3(1),   dim3(64),  0, stream>>>(ws, 0);
    k_fin1  <<<dim3(NBR), dim3(NTR), 0, stream>>>(X, out, ws);
    k_run<1><<<dim3(NBR), dim3(NTR), 0, stream>>>(X, out, ws);
    k_scan  <<<dim3(1),   dim3(64),  0, stream>>>(ws, 1);
    k_fin2  <<<dim3(NBR), dim3(NTR), 0, stream>>>(X, out, ws);
}

// Round 11
// 2248.617 us; speedup vs baseline: 1.4064x; 1.4064x over previous
//
#include <hip/hip_runtime.h>
#include <math.h>

// ---------------- problem constants (fixed by setup_inputs) ----------------
#define N_    256
#define T_    36
#define M_    50
#define P_    80
#define K_    161          // 1 + 2P
#define PADK  192          // K padded to 16*12, pad cols are zero
#define KC    12           // k-elements per lane (16 lanes per column)
#define NBR   800          // 800 blocks * 4 waves * 4 cols = 12800 columns
#define NTR   256          // 4 waves/block; C=1 -> 3200 waves = 3.1/SIMD
#define LAM_  0.1f
#define MAXIT 100

#define KM_     (K_*M_)        // 8050
#define TM_     (T_*M_)        // 1800
#define OUT_DIC 2060800        // N*K*M
#define OUT_REC 2066596        // + T*K

// ---- workspace float offsets ----
#define WS_LINV 0
#define WS_D    64             // 36*192 = 6912 floats
#define WS_ACC  8192           // 2 passes * 100 iters * 4 slots = 800 floats
#define WS_WN   9000           // 1 float (sum of wn^2 over pass-1 code)
#define WS_NIT1 9002           // int slot: pass-1 replay count (101 = none)
#define WS_NIT2 9003           // int slot: pass-2 replay count

// ---------------------------------------------------------------------------
// kernel 1: build dictionary (write dic output + padded D to ws) and
// Linv = 1/frob(DtD) using frob(DtD) == frob(D D^T)  (36x36 instead of 161^2)
// ---------------------------------------------------------------------------
__global__ __launch_bounds__(256) void k_dict(const float* __restrict__ rr,
                                              const float* __restrict__ th,
                                              float* __restrict__ out,
                                              float* __restrict__ ws) {
    __shared__ float Dl[T_*PADK];
    const int tid = threadIdx.x;
    for (int e = tid; e < T_*PADK; e += 256) {
        int t = e / PADK, k = e - (e / PADK) * PADK;
        float v = 0.f;
        if (k == 0) v = 1.f;
        else if (k <= P_)      { float r = rr[k-1];     float a = th[k-1]*(float)t;
                                 v = powf(r, (float)t) * cosf(a); }
        else if (k <= 2*P_)    { float r = rr[k-1-P_];  float a = th[k-1-P_]*(float)t;
                                 v = powf(r, (float)t) * sinf(a); }
        Dl[e] = v;
        ws[WS_D + e] = v;
        if (k < K_) out[OUT_DIC + t*K_ + k] = v;
    }
    __syncthreads();
    float loc = 0.f;
    for (int e = tid; e < T_*T_; e += 256) {
        int t1 = e / T_, t2 = e - (e / T_) * T_;
        float s = 0.f;
        for (int k = 0; k < K_; ++k) s = fmaf(Dl[t1*PADK+k], Dl[t2*PADK+k], s);
        loc = fmaf(s, s, loc);
    }
    #pragma unroll
    for (int mm = 1; mm < 64; mm <<= 1) loc += __shfl_xor(loc, mm);
    __shared__ float rb[4];
    if ((tid & 63) == 0) rb[tid >> 6] = loc;
    __syncthreads();
    if (tid == 0) {
        float tot = rb[0] + rb[1] + rb[2] + rb[3];
        ws[WS_LINV] = 1.0f / sqrtf(tot);
    }
}

// ---- DPP-based 16-lane sum (pure VALU, off the LDS pipe) -------------------
template<int CTRL>
__device__ __forceinline__ float dpp_mov(float v) {
    int p = __builtin_amdgcn_update_dpp(0, __float_as_int(v), CTRL, 0xF, 0xF, true);
    return __int_as_float(p);
}
__device__ __forceinline__ float reduce16(float z) {
    z += dpp_mov<0xB1>(z);     // quad_perm [1,0,3,2]  (xor 1)
    z += dpp_mov<0x4E>(z);     // quad_perm [2,3,0,1]  (xor 2)
    z += dpp_mov<0x141>(z);    // row_half_mirror      (other quad)
    z += dpp_mov<0x140>(z);    // row_mirror           (other 8-group)
    return z;
}

// ---------------------------------------------------------------------------
// k_run<PASS>: one reweighting pass, MAXIT iters, record conv norms (4-slot
// spread), write code. C=1 (state x,y,cm,cp,u = 60 floats, ~85 regs live).
// waves_per_eu(2,3): min-2 stops the RA's 8-waves/EU squeeze (r8: 52 VGPR +
// 15MB scratch; r9 num_vgpr(128): 44); max-3 budget 170 >= live state.
// The 4 col-groups/wave read identical LDS addresses (broadcast, free).
// PASS 0: scalar wl = lam*Linv. PASS 1: cm/cp = b -/+ wl(x1) precomputed.
// ---------------------------------------------------------------------------
template<int PASS>
__global__ __attribute__((amdgpu_flat_work_group_size(NTR, NTR),
                          amdgpu_waves_per_eu(2, 3)))
void k_run(const float* __restrict__ X,
           float* __restrict__ out,
           float* __restrict__ ws) {
    __shared__ __align__(16) float Dl[T_*PADK];
    const int tid = threadIdx.x;
    for (int e = tid; e < T_*PADK; e += NTR) Dl[e] = ws[WS_D + e];
    const float Linv = ws[WS_LINV];
    __syncthreads();

    const int lane  = tid & 63;
    const int sub   = lane & 15;
    const int gw    = (int)blockIdx.x * (NTR/64) + (tid >> 6);
    const int col   = gw*4 + (lane >> 4);          // [0, 12800), 1 col/thread
    const int n0    = col / M_;
    const int m0    = col - n0*M_;
    const int kbase = sub * KC;                    // sub>=14 -> pad region
    const float* Y0 = X + n0*TM_ + m0;

    float x[KC], y[KC], cm[KC], cp[KC];
    const float wlc = LAM_ * Linv;

    // ---- b = Linv * (D^T Ycol), stored into cm ----
    #pragma unroll
    for (int j = 0; j < KC; ++j) cm[j] = 0.f;
    #pragma unroll 2
    for (int t = 0; t < T_; ++t) {
        float yv0 = Y0[t*M_];
        const float4* dp = (const float4*)(Dl + t*PADK + kbase);
        float4 da[3] = {dp[0], dp[1], dp[2]};
        #pragma unroll
        for (int q = 0; q < 3; ++q) {
            cm[4*q+0] = fmaf(da[q].x, yv0, cm[4*q+0]);
            cm[4*q+1] = fmaf(da[q].y, yv0, cm[4*q+1]);
            cm[4*q+2] = fmaf(da[q].z, yv0, cm[4*q+2]);
            cm[4*q+3] = fmaf(da[q].w, yv0, cm[4*q+3]);
        }
    }
    #pragma unroll
    for (int j = 0; j < KC; ++j) cm[j] *= Linv;

    if (PASS == 1) {
        // wl = K*lam*Linv/||wn|| * 1/(|x1|+0.01); cm=b-wl, cp=b+wl
        float scale = ((float)K_) * (LAM_ * Linv) / sqrtf(ws[WS_WN]);
        #pragma unroll
        for (int j = 0; j < KC; ++j) {
            int kg = kbase + j;
            float x1 = (kg < K_) ? out[n0*KM_ + kg*M_ + m0] : 0.f;
            float wl = scale / (fabsf(x1) + 0.01f);
            float bb = cm[j];
            cm[j] = bb - wl;
            cp[j] = bb + wl;
        }
    }

    float tcur = 1.f;

    auto iterate = [&](float tt) -> float {
        float u[KC];
        #pragma unroll
        for (int j = 0; j < KC; ++j) u[j] = 0.f;
        #pragma unroll 2
        for (int t = 0; t < T_; ++t) {
            const float4* dp = (const float4*)(Dl + t*PADK + kbase);
            float4 da[3] = {dp[0], dp[1], dp[2]};
            float z0=0.f, z1=0.f, z2=0.f, z3=0.f;
            #pragma unroll
            for (int q = 0; q < 3; ++q) {
                z0 = fmaf(da[q].x, y[4*q+0], z0);
                z1 = fmaf(da[q].y, y[4*q+1], z1);
                z2 = fmaf(da[q].z, y[4*q+2], z2);
                z3 = fmaf(da[q].w, y[4*q+3], z3);
            }
            float z = reduce16((z0+z1) + (z2+z3));   // 16 lanes hold z_t
            #pragma unroll
            for (int q = 0; q < 3; ++q) {
                u[4*q+0] = fmaf(da[q].x, z, u[4*q+0]);
                u[4*q+1] = fmaf(da[q].y, z, u[4*q+1]);
                u[4*q+2] = fmaf(da[q].z, z, u[4*q+2]);
                u[4*q+3] = fmaf(da[q].w, z, u[4*q+3]);
            }
        }
        float ss = 0.f;
        #pragma unroll
        for (int j = 0; j < KC; ++j) {
            float v = fmaf(-Linv, u[j], y[j]);       // Ay
            float xn;
            if (PASS == 0) {
                float s = v + cm[j];                  // Ay + b
                xn = fmaxf(0.f, s - wlc) + fminf(0.f, s + wlc);
            } else {
                xn = fmaxf(0.f, v + cm[j]) + fminf(0.f, v + cp[j]);
            }
            float d = xn - x[j];
            ss   = fmaf(d, d, ss);
            y[j] = fmaf(tt, d, xn);
            x[j] = xn;
        }
        return ss;
    };

    #pragma unroll
    for (int j = 0; j < KC; ++j) { x[j] = 0.f; y[j] = 0.f; }
    float* acc = ws + WS_ACC + PASS*4*MAXIT;
    for (int i = 0; i < MAXIT; ++i) {
        float tnext = 0.5f * (1.f + sqrtf(fmaf(4.f*tcur, tcur, 1.f)));
        float tt = (tcur - 1.f) / tnext;
        tcur = tnext;
        float ss = iterate(tt);
        ss = reduce16(ss);                           // 4 DPP levels (VALU)
        ss += __shfl_xor(ss, 16);
        ss += __shfl_xor(ss, 32);
        if (lane == 0) atomicAdd(acc + i*4 + (gw & 3), ss);   // fire-and-forget
    }

    // ---- write code ----
    #pragma unroll
    for (int j = 0; j < KC; ++j) {
        int kg = kbase + j;
        if (kg < K_) out[n0*KM_ + kg*M_ + m0] = x[j];
    }
}

// ---------------------------------------------------------------------------
// helpers for the (rarely-executed) replay/finish kernels (C=1)
// ---------------------------------------------------------------------------
struct Geo { int n0, m0, kbase, sub, lane; };
__device__ __forceinline__ Geo make_geo() {
    Geo g;
    const int tid = threadIdx.x;
    g.lane = tid & 63;
    g.sub  = g.lane & 15;
    const int gw  = (int)blockIdx.x * (NTR/64) + (tid >> 6);
    const int col = gw*4 + (g.lane >> 4);
    g.n0 = col / M_;  g.m0 = col - g.n0*M_;
    g.kbase = g.sub * KC;
    return g;
}

__device__ __forceinline__ void compute_b(const float* Dl, int kbase, float Linv,
                                          const float* Y0, float (&b)[KC]) {
    #pragma unroll
    for (int j = 0; j < KC; ++j) b[j] = 0.f;
    #pragma unroll 2
    for (int t = 0; t < T_; ++t) {
        float yv0 = Y0[t*M_];
        const float4* dp = (const float4*)(Dl + t*PADK + kbase);
        float4 da[3] = {dp[0], dp[1], dp[2]};
        #pragma unroll
        for (int q = 0; q < 3; ++q) {
            b[4*q+0] = fmaf(da[q].x, yv0, b[4*q+0]);
            b[4*q+1] = fmaf(da[q].y, yv0, b[4*q+1]);
            b[4*q+2] = fmaf(da[q].z, yv0, b[4*q+2]);
            b[4*q+3] = fmaf(da[q].w, yv0, b[4*q+3]);
        }
    }
    #pragma unroll
    for (int j = 0; j < KC; ++j) b[j] *= Linv;
}

// generic FISTA run with per-element cm/cp (used only on replay paths)
__device__ __forceinline__ void run_fista(const float* Dl, int kbase, float Linv,
                                          const float (&cmv)[KC],
                                          const float (&cpv)[KC],
                                          float (&x)[KC], int nit) {
    float y[KC];
    #pragma unroll
    for (int j = 0; j < KC; ++j) { x[j] = 0.f; y[j] = 0.f; }
    float tcur = 1.f;
    for (int i = 0; i < nit; ++i) {
        float tnext = 0.5f * (1.f + sqrtf(fmaf(4.f*tcur, tcur, 1.f)));
        float tt = (tcur - 1.f) / tnext;
        tcur = tnext;
        float u[KC];
        #pragma unroll
        for (int j = 0; j < KC; ++j) u[j] = 0.f;
        #pragma unroll 2
        for (int t = 0; t < T_; ++t) {
            const float4* dp = (const float4*)(Dl + t*PADK + kbase);
            float4 da[3] = {dp[0], dp[1], dp[2]};
            float z0=0.f, z1=0.f, z2=0.f, z3=0.f;
            #pragma unroll
            for (int q = 0; q < 3; ++q) {
                z0 = fmaf(da[q].x, y[4*q+0], z0);
                z1 = fmaf(da[q].y, y[4*q+1], z1);
                z2 = fmaf(da[q].z, y[4*q+2], z2);
                z3 = fmaf(da[q].w, y[4*q+3], z3);
            }
            float z = reduce16((z0+z1) + (z2+z3));
            #pragma unroll
            for (int q = 0; q < 3; ++q) {
                u[4*q+0] = fmaf(da[q].x, z, u[4*q+0]);
                u[4*q+1] = fmaf(da[q].y, z, u[4*q+1]);
                u[4*q+2] = fmaf(da[q].z, z, u[4*q+2]);
                u[4*q+3] = fmaf(da[q].w, z, u[4*q+3]);
            }
        }
        #pragma unroll
        for (int j = 0; j < KC; ++j) {
            float v = fmaf(-Linv, u[j], y[j]);
            float xn = fmaxf(0.f, v + cmv[j]) + fminf(0.f, v + cpv[j]);
            float d = xn - x[j];
            y[j] = fmaf(tt, d, xn);
            x[j] = xn;
        }
    }
}

__device__ __forceinline__ void write_code_g(const Geo& g, const float (&x)[KC],
                                             float* out) {
    #pragma unroll
    for (int j = 0; j < KC; ++j) {
        int kg = g.kbase + j;
        if (kg < K_) out[g.n0*KM_ + kg*M_ + g.m0] = x[j];
    }
}
__device__ __forceinline__ void load_code_g(const Geo& g, float (&x)[KC],
                                            const float* out) {
    #pragma unroll
    for (int j = 0; j < KC; ++j) {
        int kg = g.kbase + j;
        x[j] = (kg < K_) ? out[g.n0*KM_ + kg*M_ + g.m0] : 0.f;
    }
}

// ---------------------------------------------------------------------------
// k_scan: find first iter with global ||dx||^2 < (tol*K)^2 (4 slots per iter)
// ---------------------------------------------------------------------------
__global__ void k_scan(float* __restrict__ ws, int pass) {
    const float THR2 = (1e-5f * (float)K_) * (1e-5f * (float)K_);
    int lane = threadIdx.x;
    const float* acc = ws + WS_ACC + pass*4*MAXIT;
    int best = MAXIT + 1;
    for (int i = lane; i < MAXIT; i += 64) {
        float a = (acc[i*4] + acc[i*4+1]) + (acc[i*4+2] + acc[i*4+3]);
        if (a < THR2) best = min(best, i + 1);
    }
    #pragma unroll
    for (int mm = 1; mm < 64; mm <<= 1) best = min(best, __shfl_xor(best, mm));
    if (lane == 0) ((int*)ws)[pass == 0 ? WS_NIT1 : WS_NIT2] = best;
}

// ---------------------------------------------------------------------------
// k_fin1: if pass-1 converged early, replay nit1 iters and rewrite code;
// then accumulate ||wn||^2 into WS_WN. (Expected: no replay -> cheap.)
// ---------------------------------------------------------------------------
__global__ __launch_bounds__(NTR, 1) void k_fin1(const float* __restrict__ X,
                                                 float* __restrict__ out,
                                                 float* __restrict__ ws) {
    __shared__ __align__(16) float Dl[T_*PADK];
    for (int e = threadIdx.x; e < T_*PADK; e += NTR) Dl[e] = ws[WS_D + e];
    const float Linv = ws[WS_LINV];
    __syncthreads();

    Geo g = make_geo();
    const int nit1 = ((const int*)ws)[WS_NIT1];
    float x[KC];

    if (nit1 <= MAXIT) {
        float b[KC], cmv[KC], cpv[KC];
        compute_b(Dl, g.kbase, Linv, X + g.n0*TM_ + g.m0, b);
        const float wlc = LAM_ * Linv;
        #pragma unroll
        for (int j = 0; j < KC; ++j) { cmv[j] = b[j] - wlc; cpv[j] = b[j] + wlc; }
        run_fista(Dl, g.kbase, Linv, cmv, cpv, x, nit1);
        write_code_g(g, x, out);
    } else {
        load_code_g(g, x, out);
    }

    float loc = 0.f;
    #pragma unroll
    for (int j = 0; j < KC; ++j) {
        if (g.kbase + j < K_) {
            float wn = 1.0f / (fabsf(x[j]) + 0.01f);
            loc = fmaf(wn, wn, loc);
        }
    }
    #pragma unroll
    for (int mm = 1; mm < 64; mm <<= 1) loc += __shfl_xor(loc, mm);
    if (g.lane == 0) atomicAdd(ws + WS_WN, loc);
}

// ---------------------------------------------------------------------------
// k_fin2: if pass-2 converged early, re-derive pass-1 x, recompute weights,
// replay nit2 iters, rewrite code. Always write reconst from final code.
// ---------------------------------------------------------------------------
__global__ __launch_bounds__(NTR, 1) void k_fin2(const float* __restrict__ X,
                                                 float* __restrict__ out,
                                                 float* __restrict__ ws) {
    __shared__ __align__(16) float Dl[T_*PADK];
    for (int e = threadIdx.x; e < T_*PADK; e += NTR) Dl[e] = ws[WS_D + e];
    const float Linv = ws[WS_LINV];
    __syncthreads();

    Geo g = make_geo();
    const int nit1 = ((const int*)ws)[WS_NIT1];
    const int nit2 = ((const int*)ws)[WS_NIT2];
    float x[KC];

    if (nit2 <= MAXIT) {
        float b[KC], cmv[KC], cpv[KC];
        compute_b(Dl, g.kbase, Linv, X + g.n0*TM_ + g.m0, b);
        const float wlc = LAM_ * Linv;
        #pragma unroll
        for (int j = 0; j < KC; ++j) { cmv[j] = b[j] - wlc; cpv[j] = b[j] + wlc; }
        int nrep1 = nit1 <= MAXIT ? nit1 : MAXIT;
        run_fista(Dl, g.kbase, Linv, cmv, cpv, x, nrep1);
        float scale = ((float)K_) * (LAM_ * Linv) / sqrtf(ws[WS_WN]);
        #pragma unroll
        for (int j = 0; j < KC; ++j) {
            float wl = scale / (fabsf(x[j]) + 0.01f);
            cmv[j] = b[j] - wl;
            cpv[j] = b[j] + wl;
        }
        run_fista(Dl, g.kbase, Linv, cmv, cpv, x, nit2);
        write_code_g(g, x, out);
    } else {
        load_code_g(g, x, out);
    }

    // ---- reconst = D @ code ----
    #pragma unroll 2
    for (int t = 0; t < T_; ++t) {
        const float4* dp = (const float4*)(Dl + t*PADK + g.kbase);
        float4 da[3] = {dp[0], dp[1], dp[2]};
        float z0=0.f, z1=0.f, z2=0.f, z3=0.f;
        #pragma unroll
        for (int q = 0; q < 3; ++q) {
            z0 = fmaf(da[q].x, x[4*q+0], z0);
            z1 = fmaf(da[q].y, x[4*q+1], z1);
            z2 = fmaf(da[q].z, x[4*q+2], z2);
            z3 = fmaf(da[q].w, x[4*q+3], z3);
        }
        float z = reduce16((z0+z1) + (z2+z3));
        if (g.sub == (t & 15)) {
            out[OUT_REC + g.n0*TM_ + t*M_ + g.m0] = z;
        }
    }
}

// ---------------------------------------------------------------------------
extern "C" void kernel_launch(void* const* d_in, const int* in_sizes, int n_in,
                              void* d_out, int out_size, void* d_ws, size_t ws_size,
                              hipStream_t stream) {
    const float* X  = (const float*)d_in[0];
    const float* rr = (const float*)d_in[1];
    const float* th = (const float*)d_in[2];
    float* out = (float*)d_out;
    float* ws  = (float*)d_ws;

    // zero conv accumulators + wn accumulator + niter slots (every call)
    hipMemsetAsync((char*)d_ws + WS_ACC*sizeof(float), 0, 4096, stream);
    k_dict  <<<dim3(1),   dim3(256), 0, stream>>>(rr, th, out, ws);
    k_run<0><<<dim3(NBR), dim3(NTR), 0, stream>>>(X, out, ws);
    k_scan  <<<dim3(1),   dim3(64),  0, stream>>>(ws, 0);
    k_fin1  <<<dim3(NBR), dim3(NTR), 0, stream>>>(X, out, ws);
    k_run<1><<<dim3(NBR), dim3(NTR), 0, stream>>>(X, out, ws);
    k_scan  <<<dim3(1),   dim3(64),  0, stream>>>(ws, 1);
    k_fin2  <<<dim3(NBR), dim3(NTR), 0, stream>>>(X, out, ws);
}